// Round 2
// baseline (1668.528 us; speedup 1.0000x reference)
//
#include <hip/hip_runtime.h>
#include <hip/hip_bf16.h>

typedef unsigned short ushort_t;
typedef __attribute__((ext_vector_type(8))) short short8;
typedef __attribute__((ext_vector_type(4))) float f32x4;
typedef __attribute__((ext_vector_type(4))) unsigned int uint4v;

#define NQ      2048
#define ND      512
#define NDB     100000
#define TOPK    10
#define NCHUNK  49
#define CHUNK_N 2048                  // 16 tiles * 128
#define NPAD    (NCHUNK * CHUNK_N)    // 100352 >= 100000
#define QTILES  (NQ / 128)            // 16
#define NTILES  (CHUNK_N / 128)       // 16
#define LDAS    36                    // score buffer leading dim (f32)

// async global->LDS, 16B per lane, wave-uniform LDS base + lane*16
#define GL2LDS(gp, lp) __builtin_amdgcn_global_load_lds(                      \
    (const __attribute__((address_space(1))) void*)(gp),                     \
    (__attribute__((address_space(3))) void*)(lp), 16, 0, 0)

// ---------- fp32 -> bf16 (round to nearest even) ----------
static __device__ inline ushort_t f2bf(float x) {
    unsigned u = __float_as_uint(x);
    unsigned r = (u + 0x7FFFu + ((u >> 16) & 1u)) >> 16;
    return (ushort_t)r;
}

// ---------- row L2-normalize, fp32 -> bf16, one wave per row; zero-fill pad rows ----------
__global__ void normalize_rows(const float* __restrict__ in, ushort_t* __restrict__ out,
                               int nvalid, int ntotal) {
    int row  = blockIdx.x * 4 + (threadIdx.x >> 6);
    int lane = threadIdx.x & 63;
    if (row >= ntotal) return;
    uint4v pk;
    if (row >= nvalid) {
        pk[0] = 0u; pk[1] = 0u; pk[2] = 0u; pk[3] = 0u;
    } else {
        const float4* src = reinterpret_cast<const float4*>(in + (size_t)row * ND);
        float4 v0 = src[lane * 2];
        float4 v1 = src[lane * 2 + 1];
        float s = v0.x*v0.x + v0.y*v0.y + v0.z*v0.z + v0.w*v0.w
                + v1.x*v1.x + v1.y*v1.y + v1.z*v1.z + v1.w*v1.w;
        #pragma unroll
        for (int off = 32; off; off >>= 1) s += __shfl_xor(s, off, 64);
        float r = rsqrtf(s);
        pk[0] = (unsigned)f2bf(v0.x * r) | ((unsigned)f2bf(v0.y * r) << 16);
        pk[1] = (unsigned)f2bf(v0.z * r) | ((unsigned)f2bf(v0.w * r) << 16);
        pk[2] = (unsigned)f2bf(v1.x * r) | ((unsigned)f2bf(v1.y * r) << 16);
        pk[3] = (unsigned)f2bf(v1.z * r) | ((unsigned)f2bf(v1.w * r) << 16);
    }
    *reinterpret_cast<uint4v*>(out + (size_t)row * ND + lane * 8) = pk;
}

__device__ inline void topk_insert(float (&top)[TOPK], float x) {
    #pragma unroll
    for (int i = 0; i < TOPK; ++i) {
        float mx = fmaxf(top[i], x);
        x = fminf(top[i], x);
        top[i] = mx;
    }
}

// ---------- fused GEMM + per-chunk top-10 ----------
// grid: NCHUNK * QTILES blocks, 256 threads (4 waves, 2x2 wave grid, 64x64 per wave)
__global__ __launch_bounds__(256)
void knn_chunk(const ushort_t* __restrict__ qb, const ushort_t* __restrict__ dbb,
               float* __restrict__ partial) {
    const int bid = blockIdx.x;
    const int qt = bid & (QTILES - 1);
    const int nc = bid >> 4;           // QTILES == 16
    const int t = threadIdx.x, lane = t & 63, wv = t >> 6;
    const int wr = wv >> 1, wc = wv & 1;

    // linear bf16 tiles (required by global_load_lds) + separate f32 score buffer
    __shared__ __align__(16) ushort_t As[128 * 64];
    __shared__ __align__(16) ushort_t Bs[128 * 64];
    __shared__ __align__(16) float    Ss[128 * LDAS];

    float top[TOPK];
    #pragma unroll
    for (int i = 0; i < TOPK; ++i) top[i] = -1e30f;

    const int qbase = qt * 128;
    const size_t nchunkbase = (size_t)nc * CHUNK_N;
    const int cb = wv * 256;                 // wave's 16B-chunk base within the 1024-chunk tile

    for (int nt = 0; nt < NTILES; ++nt) {
        const size_t nbase = nchunkbase + nt * 128;
        f32x4 acc[4][4];
        #pragma unroll
        for (int a = 0; a < 4; ++a)
            #pragma unroll
            for (int b = 0; b < 4; ++b)
                acc[a][b] = (f32x4){0.f, 0.f, 0.f, 0.f};

        const ushort_t* aseg = qb  + (size_t)qbase * ND;
        const ushort_t* bseg = dbb + nbase * ND;

        #pragma unroll 1
        for (int ks = 0; ks < 8; ++ks) {
            const int kbase = ks * 64;
            __syncthreads();   // previous tile's frags consumed / scores scanned
            #pragma unroll
            for (int i = 0; i < 4; ++i) {
                const int cid = cb + i * 64 + lane;       // this lane's chunk
                const int row = cid >> 3;
                const int c   = (cid & 7) ^ (row & 7);    // inverse swizzle on global source
                const size_t go = (size_t)row * ND + kbase + c * 8;
                GL2LDS(aseg + go, As + (cb + i * 64) * 8);
                GL2LDS(bseg + go, Bs + (cb + i * 64) * 8);
            }
            __syncthreads();   // vmcnt(0)+barrier: tile staged
            #pragma unroll
            for (int ksub = 0; ksub < 2; ++ksub) {
                const int cgrp = ksub * 4 + (lane >> 4);  // logical 16B chunk in row
                short8 af[4], bf[4];
                #pragma unroll
                for (int qs = 0; qs < 4; ++qs) {
                    const int ar = wr * 64 + qs * 16 + (lane & 15);
                    af[qs] = *reinterpret_cast<const short8*>(As + ar * 64 + ((cgrp ^ (ar & 7)) * 8));
                }
                #pragma unroll
                for (int ns = 0; ns < 4; ++ns) {
                    const int br = wc * 64 + ns * 16 + (lane & 15);
                    bf[ns] = *reinterpret_cast<const short8*>(Bs + br * 64 + ((cgrp ^ (br & 7)) * 8));
                }
                #pragma unroll
                for (int qs = 0; qs < 4; ++qs)
                    #pragma unroll
                    for (int ns = 0; ns < 4; ++ns)
                        acc[qs][ns] = __builtin_amdgcn_mfma_f32_16x16x32_bf16(af[qs], bf[ns], acc[qs][ns], 0, 0, 0);
            }
        }

        // selection: four 32-col passes through the f32 score buffer
        #pragma unroll 1
        for (int p2 = 0; p2 < 4; ++p2) {
            __syncthreads();
            if (wc == (p2 >> 1)) {
                #pragma unroll
                for (int qs = 0; qs < 4; ++qs)
                    #pragma unroll
                    for (int nn = 0; nn < 2; ++nn) {
                        const int ns = (p2 & 1) * 2 + nn;
                        #pragma unroll
                        for (int r = 0; r < 4; ++r)
                            Ss[(wr * 64 + qs * 16 + (lane >> 4) * 4 + r) * LDAS + nn * 16 + (lane & 15)] = acc[qs][ns][r];
                    }
            }
            __syncthreads();
            const int q = t >> 1, part = t & 1;
            const f32x4* rowp = reinterpret_cast<const f32x4*>(Ss + q * LDAS + part * 16);
            #pragma unroll
            for (int j = 0; j < 4; ++j) {
                f32x4 v = rowp[j];
                float m = fmaxf(fmaxf(v[0], v[1]), fmaxf(v[2], v[3]));
                if (m > top[TOPK - 1]) {
                    #pragma unroll
                    for (int e = 0; e < 4; ++e)
                        if (v[e] > top[TOPK - 1]) topk_insert(top, v[e]);
                }
            }
        }
    }

    // block-level merge: 2 partial top-10s per query -> 10
    __syncthreads();
    {
        const int q = t >> 1, part = t & 1;
        #pragma unroll
        for (int i = 0; i < TOPK; ++i) Ss[q * 20 + part * 10 + i] = top[i];
    }
    __syncthreads();
    if (t < 128) {
        float best[TOPK];
        #pragma unroll
        for (int i = 0; i < TOPK; ++i) best[i] = -1e30f;
        for (int i = 0; i < 20; ++i) {
            float x = Ss[t * 20 + i];
            if (x > best[TOPK - 1]) topk_insert(best, x);
        }
        float* dst = partial + ((size_t)nc * NQ + qbase + t) * TOPK;
        #pragma unroll
        for (int i = 0; i < TOPK; ++i) dst[i] = best[i];
    }
}

// ---------- merge chunks, emit k-th squared distance ----------
__global__ void final_merge(const float* __restrict__ partial, float* __restrict__ out) {
    int q = blockIdx.x * 256 + threadIdx.x;
    if (q >= NQ) return;
    float top[TOPK];
    #pragma unroll
    for (int i = 0; i < TOPK; ++i) top[i] = -1e30f;
    for (int c = 0; c < NCHUNK; ++c) {
        const float* p = partial + ((size_t)c * NQ + q) * TOPK;
        #pragma unroll
        for (int i = 0; i < TOPK; ++i) {
            float x = p[i];
            if (x > top[TOPK - 1]) topk_insert(top, x);
        }
    }
    out[q] = 2.0f - 2.0f * top[TOPK - 1];
}

extern "C" void kernel_launch(void* const* d_in, const int* in_sizes, int n_in,
                              void* d_out, int out_size, void* d_ws, size_t ws_size,
                              hipStream_t stream) {
    const float* features = (const float*)d_in[0];
    const float* dbf      = (const float*)d_in[2];
    float* out = (float*)d_out;

    ushort_t* dbb = (ushort_t*)d_ws;                         // [NPAD][512] bf16   ~102.8 MB
    ushort_t* qbn = dbb + (size_t)NPAD * ND;                 // [2048][512] bf16   ~2 MB
    float* partial = (float*)(qbn + (size_t)NQ * ND);        // [NCHUNK][2048][10] ~4.0 MB

    normalize_rows<<<NPAD / 4, 256, 0, stream>>>(dbf, dbb, NDB, NPAD);
    normalize_rows<<<NQ / 4, 256, 0, stream>>>(features, qbn, NQ, NQ);
    knn_chunk<<<NCHUNK * QTILES, 256, 0, stream>>>(qbn, dbb, partial);
    final_merge<<<(NQ + 255) / 256, 256, 0, stream>>>(partial, out);
}

// Round 3
// 699.050 us; speedup vs baseline: 2.3869x; 2.3869x over previous
//
#include <hip/hip_runtime.h>
#include <hip/hip_bf16.h>

typedef unsigned short ushort_t;
typedef __attribute__((ext_vector_type(8))) short short8;
typedef __attribute__((ext_vector_type(4))) float f32x4;
typedef __attribute__((ext_vector_type(4))) unsigned int uint4v;

#define NQ      2048
#define ND      512
#define NDB     100000
#define TOPK    10
#define NCHUNK  49
#define CHUNK_N 2048                  // 16 tiles * 128
#define NPAD    (NCHUNK * CHUNK_N)    // 100352 >= 100000
#define QTILES  (NQ / 128)            // 16
#define NTILES  (CHUNK_N / 128)       // 16
#define LDAS    36                    // score buffer leading dim (f32)

// async global->LDS, 16B per lane, wave-uniform LDS base + lane*16
#define GL2LDS(gp, lp) __builtin_amdgcn_global_load_lds(                      \
    (const __attribute__((address_space(1))) void*)(gp),                     \
    (__attribute__((address_space(3))) void*)(lp), 16, 0, 0)

// ---------- fp32 -> bf16 (round to nearest even) ----------
static __device__ inline ushort_t f2bf(float x) {
    unsigned u = __float_as_uint(x);
    unsigned r = (u + 0x7FFFu + ((u >> 16) & 1u)) >> 16;
    return (ushort_t)r;
}

// ---------- row L2-normalize, fp32 -> bf16, one wave per row; zero-fill pad rows ----------
__global__ void normalize_rows(const float* __restrict__ in, ushort_t* __restrict__ out,
                               int nvalid, int ntotal) {
    int row  = blockIdx.x * 4 + (threadIdx.x >> 6);
    int lane = threadIdx.x & 63;
    if (row >= ntotal) return;
    uint4v pk;
    if (row >= nvalid) {
        pk[0] = 0u; pk[1] = 0u; pk[2] = 0u; pk[3] = 0u;
    } else {
        const float4* src = reinterpret_cast<const float4*>(in + (size_t)row * ND);
        float4 v0 = src[lane * 2];
        float4 v1 = src[lane * 2 + 1];
        float s = v0.x*v0.x + v0.y*v0.y + v0.z*v0.z + v0.w*v0.w
                + v1.x*v1.x + v1.y*v1.y + v1.z*v1.z + v1.w*v1.w;
        #pragma unroll
        for (int off = 32; off; off >>= 1) s += __shfl_xor(s, off, 64);
        float r = rsqrtf(s);
        pk[0] = (unsigned)f2bf(v0.x * r) | ((unsigned)f2bf(v0.y * r) << 16);
        pk[1] = (unsigned)f2bf(v0.z * r) | ((unsigned)f2bf(v0.w * r) << 16);
        pk[2] = (unsigned)f2bf(v1.x * r) | ((unsigned)f2bf(v1.y * r) << 16);
        pk[3] = (unsigned)f2bf(v1.z * r) | ((unsigned)f2bf(v1.w * r) << 16);
    }
    *reinterpret_cast<uint4v*>(out + (size_t)row * ND + lane * 8) = pk;
}

__device__ inline void topk_insert(float (&top)[TOPK], float x) {
    #pragma unroll
    for (int i = 0; i < TOPK; ++i) {
        float mx = fmaxf(top[i], x);
        x = fminf(top[i], x);
        top[i] = mx;
    }
}

// ---------- fused GEMM + per-chunk top-10 ----------
// grid: NCHUNK * QTILES blocks, 256 threads (4 waves, 2x2 wave grid, 64x64 per wave)
__global__ __launch_bounds__(256)
void knn_chunk(const ushort_t* __restrict__ qb, const ushort_t* __restrict__ dbb,
               float* __restrict__ partial) {
    const int bid = blockIdx.x;
    const int qt = bid & (QTILES - 1);
    const int nc = bid >> 4;           // QTILES == 16
    const int t = threadIdx.x, lane = t & 63, wv = t >> 6;
    const int wr = wv >> 1, wc = wv & 1;

    // linear bf16 tiles (required by global_load_lds) + separate f32 score buffer
    __shared__ __align__(16) ushort_t As[128 * 64];
    __shared__ __align__(16) ushort_t Bs[128 * 64];
    __shared__ __align__(16) float    Ss[128 * LDAS];

    float top[TOPK];
    #pragma unroll
    for (int i = 0; i < TOPK; ++i) top[i] = -1e30f;

    const int qbase = qt * 128;
    const size_t nchunkbase = (size_t)nc * CHUNK_N;
    const int cb = wv * 256;                 // wave's 16B-chunk base within the 1024-chunk tile

    for (int nt = 0; nt < NTILES; ++nt) {
        const size_t nbase = nchunkbase + nt * 128;
        f32x4 acc[4][4];
        #pragma unroll
        for (int a = 0; a < 4; ++a)
            #pragma unroll
            for (int b = 0; b < 4; ++b)
                acc[a][b] = (f32x4){0.f, 0.f, 0.f, 0.f};

        const ushort_t* aseg = qb  + (size_t)qbase * ND;
        const ushort_t* bseg = dbb + nbase * ND;

        #pragma unroll 1
        for (int ks = 0; ks < 8; ++ks) {
            const int kbase = ks * 64;
            __syncthreads();   // previous tile's frags consumed / scores scanned
            #pragma unroll
            for (int i = 0; i < 4; ++i) {
                const int cid = cb + i * 64 + lane;       // this lane's chunk
                const int row = cid >> 3;
                const int c   = (cid & 7) ^ (row & 7);    // inverse swizzle on global source
                const size_t go = (size_t)row * ND + kbase + c * 8;
                GL2LDS(aseg + go, As + (cb + i * 64) * 8);
                GL2LDS(bseg + go, Bs + (cb + i * 64) * 8);
            }
            __syncthreads();   // vmcnt(0)+barrier: tile staged
            #pragma unroll
            for (int ksub = 0; ksub < 2; ++ksub) {
                const int cgrp = ksub * 4 + (lane >> 4);  // logical 16B chunk in row
                short8 af[4], bf[4];
                #pragma unroll
                for (int qs = 0; qs < 4; ++qs) {
                    const int ar = wr * 64 + qs * 16 + (lane & 15);
                    af[qs] = *reinterpret_cast<const short8*>(As + ar * 64 + ((cgrp ^ (ar & 7)) * 8));
                }
                #pragma unroll
                for (int ns = 0; ns < 4; ++ns) {
                    const int br = wc * 64 + ns * 16 + (lane & 15);
                    bf[ns] = *reinterpret_cast<const short8*>(Bs + br * 64 + ((cgrp ^ (br & 7)) * 8));
                }
                #pragma unroll
                for (int qs = 0; qs < 4; ++qs)
                    #pragma unroll
                    for (int ns = 0; ns < 4; ++ns)
                        acc[qs][ns] = __builtin_amdgcn_mfma_f32_16x16x32_bf16(af[qs], bf[ns], acc[qs][ns], 0, 0, 0);
            }
        }

        // selection: four 32-col passes through the f32 score buffer.
        // FULLY UNROLLED so every acc[][] index is compile-time (rule #20:
        // runtime-indexed ext_vector arrays demote to scratch -> 5.7 GB spill in R2).
        #pragma unroll
        for (int p2 = 0; p2 < 4; ++p2) {
            __syncthreads();
            if (wc == (p2 >> 1)) {
                #pragma unroll
                for (int qs = 0; qs < 4; ++qs)
                    #pragma unroll
                    for (int nn = 0; nn < 2; ++nn) {
                        const int ns = (p2 & 1) * 2 + nn;
                        #pragma unroll
                        for (int r = 0; r < 4; ++r)
                            Ss[(wr * 64 + qs * 16 + (lane >> 4) * 4 + r) * LDAS + nn * 16 + (lane & 15)] = acc[qs][ns][r];
                    }
            }
            __syncthreads();
            const int q = t >> 1, part = t & 1;
            const f32x4* rowp = reinterpret_cast<const f32x4*>(Ss + q * LDAS + part * 16);
            #pragma unroll
            for (int j = 0; j < 4; ++j) {
                f32x4 v = rowp[j];
                float m = fmaxf(fmaxf(v[0], v[1]), fmaxf(v[2], v[3]));
                if (m > top[TOPK - 1]) {
                    #pragma unroll
                    for (int e = 0; e < 4; ++e)
                        if (v[e] > top[TOPK - 1]) topk_insert(top, v[e]);
                }
            }
        }
    }

    // block-level merge: 2 partial top-10s per query -> 10
    __syncthreads();
    {
        const int q = t >> 1, part = t & 1;
        #pragma unroll
        for (int i = 0; i < TOPK; ++i) Ss[q * 20 + part * 10 + i] = top[i];
    }
    __syncthreads();
    if (t < 128) {
        float best[TOPK];
        #pragma unroll
        for (int i = 0; i < TOPK; ++i) best[i] = -1e30f;
        for (int i = 0; i < 20; ++i) {
            float x = Ss[t * 20 + i];
            if (x > best[TOPK - 1]) topk_insert(best, x);
        }
        float* dst = partial + ((size_t)nc * NQ + qbase + t) * TOPK;
        #pragma unroll
        for (int i = 0; i < TOPK; ++i) dst[i] = best[i];
    }
}

// ---------- merge chunks, emit k-th squared distance ----------
__global__ void final_merge(const float* __restrict__ partial, float* __restrict__ out) {
    int q = blockIdx.x * 256 + threadIdx.x;
    if (q >= NQ) return;
    float top[TOPK];
    #pragma unroll
    for (int i = 0; i < TOPK; ++i) top[i] = -1e30f;
    for (int c = 0; c < NCHUNK; ++c) {
        const float* p = partial + ((size_t)c * NQ + q) * TOPK;
        #pragma unroll
        for (int i = 0; i < TOPK; ++i) {
            float x = p[i];
            if (x > top[TOPK - 1]) topk_insert(top, x);
        }
    }
    out[q] = 2.0f - 2.0f * top[TOPK - 1];
}

extern "C" void kernel_launch(void* const* d_in, const int* in_sizes, int n_in,
                              void* d_out, int out_size, void* d_ws, size_t ws_size,
                              hipStream_t stream) {
    const float* features = (const float*)d_in[0];
    const float* dbf      = (const float*)d_in[2];
    float* out = (float*)d_out;

    ushort_t* dbb = (ushort_t*)d_ws;                         // [NPAD][512] bf16   ~102.8 MB
    ushort_t* qbn = dbb + (size_t)NPAD * ND;                 // [2048][512] bf16   ~2 MB
    float* partial = (float*)(qbn + (size_t)NQ * ND);        // [NCHUNK][2048][10] ~4.0 MB

    normalize_rows<<<NPAD / 4, 256, 0, stream>>>(dbf, dbb, NDB, NPAD);
    normalize_rows<<<NQ / 4, 256, 0, stream>>>(features, qbn, NQ, NQ);
    knn_chunk<<<NCHUNK * QTILES, 256, 0, stream>>>(qbn, dbb, partial);
    final_merge<<<(NQ + 255) / 256, 256, 0, stream>>>(partial, out);
}

// Round 4
// 588.347 us; speedup vs baseline: 2.8360x; 1.1882x over previous
//
#include <hip/hip_runtime.h>
#include <hip/hip_bf16.h>

typedef unsigned short ushort_t;
typedef __attribute__((ext_vector_type(8))) short short8;
typedef __attribute__((ext_vector_type(4))) float f32x4;
typedef __attribute__((ext_vector_type(4))) unsigned int uint4v;

#define NQ      2048
#define ND      512
#define NDB     100000
#define TOPK    10
#define NCHUNK  49
#define CHUNK_N 2048                  // 16 tiles * 128
#define NPAD    (NCHUNK * CHUNK_N)    // 100352 >= 100000
#define QTILES  (NQ / 128)            // 16
#define NTILES  (CHUNK_N / 128)       // 16

// async global->LDS, 16B per lane, wave-uniform LDS base + lane*16
#define GL2LDS(gp, lp) __builtin_amdgcn_global_load_lds(                      \
    (const __attribute__((address_space(1))) void*)(gp),                     \
    (__attribute__((address_space(3))) void*)(lp), 16, 0, 0)

// ---------- fp32 -> bf16 (round to nearest even) ----------
static __device__ inline ushort_t f2bf(float x) {
    unsigned u = __float_as_uint(x);
    unsigned r = (u + 0x7FFFu + ((u >> 16) & 1u)) >> 16;
    return (ushort_t)r;
}

// ---------- row L2-normalize, fp32 -> bf16, one wave per row; zero-fill pad rows ----------
__global__ void normalize_rows(const float* __restrict__ in, ushort_t* __restrict__ out,
                               int nvalid, int ntotal) {
    int row  = blockIdx.x * 4 + (threadIdx.x >> 6);
    int lane = threadIdx.x & 63;
    if (row >= ntotal) return;
    uint4v pk;
    if (row >= nvalid) {
        pk[0] = 0u; pk[1] = 0u; pk[2] = 0u; pk[3] = 0u;
    } else {
        const float4* src = reinterpret_cast<const float4*>(in + (size_t)row * ND);
        float4 v0 = src[lane * 2];
        float4 v1 = src[lane * 2 + 1];
        float s = v0.x*v0.x + v0.y*v0.y + v0.z*v0.z + v0.w*v0.w
                + v1.x*v1.x + v1.y*v1.y + v1.z*v1.z + v1.w*v1.w;
        #pragma unroll
        for (int off = 32; off; off >>= 1) s += __shfl_xor(s, off, 64);
        float r = rsqrtf(s);
        pk[0] = (unsigned)f2bf(v0.x * r) | ((unsigned)f2bf(v0.y * r) << 16);
        pk[1] = (unsigned)f2bf(v0.z * r) | ((unsigned)f2bf(v0.w * r) << 16);
        pk[2] = (unsigned)f2bf(v1.x * r) | ((unsigned)f2bf(v1.y * r) << 16);
        pk[3] = (unsigned)f2bf(v1.z * r) | ((unsigned)f2bf(v1.w * r) << 16);
    }
    *reinterpret_cast<uint4v*>(out + (size_t)row * ND + lane * 8) = pk;
}

__device__ inline void topk_insert(float (&top)[TOPK], float x) {
    #pragma unroll
    for (int i = 0; i < TOPK; ++i) {
        float mx = fmaxf(top[i], x);
        x = fminf(top[i], x);
        top[i] = mx;
    }
}

// ---------- fused GEMM + per-chunk top-10, register-resident selection ----------
// grid: NCHUNK * QTILES blocks, 256 threads (4 waves).
// Wave wv owns queries [wv*32, wv*32+32) x all 128 n of the tile.
// SWAPPED mfma(B,A): acc[qs][ns][r] = score[q = qs*16 + (lane&15)][n = ns*16 + (lane>>4)*4 + r]
// -> each thread's candidates are for a FIXED query per qs: top-10 stays in registers.
__global__ __launch_bounds__(256, 3)
void knn_chunk(const ushort_t* __restrict__ qb, const ushort_t* __restrict__ dbb,
               float* __restrict__ partial) {
    const int bid = blockIdx.x;
    const int qt = bid & (QTILES - 1);
    const int nc = bid >> 4;           // QTILES == 16
    const int t = threadIdx.x, lane = t & 63, wv = t >> 6;

    // linear bf16 tiles (required by global_load_lds), both-sides XOR swizzle
    __shared__ __align__(16) ushort_t As[128 * 64];
    __shared__ __align__(16) ushort_t Bs[128 * 64];

    float top[2][TOPK];
    #pragma unroll
    for (int qs = 0; qs < 2; ++qs)
        #pragma unroll
        for (int i = 0; i < TOPK; ++i) top[qs][i] = -1e30f;

    const int qbase = qt * 128;
    const size_t nchunkbase = (size_t)nc * CHUNK_N;
    const int cb = wv * 256;                 // wave's 16B-chunk base within the 1024-chunk tile
    const ushort_t* aseg = qb + (size_t)qbase * ND;

    for (int nt = 0; nt < NTILES; ++nt) {
        const ushort_t* bseg = dbb + (nchunkbase + nt * 128) * ND;
        f32x4 acc[2][8];
        #pragma unroll
        for (int a = 0; a < 2; ++a)
            #pragma unroll
            for (int b = 0; b < 8; ++b)
                acc[a][b] = (f32x4){0.f, 0.f, 0.f, 0.f};

        #pragma unroll 1
        for (int ks = 0; ks < 8; ++ks) {
            const int kbase = ks * 64;
            __syncthreads();   // previous sub-tile's frags consumed
            #pragma unroll
            for (int i = 0; i < 4; ++i) {
                const int cid = cb + i * 64 + lane;       // this lane's chunk
                const int row = cid >> 3;
                const int c   = (cid & 7) ^ (row & 7);    // inverse swizzle on global source
                const size_t go = (size_t)row * ND + kbase + c * 8;
                GL2LDS(aseg + go, As + (cb + i * 64) * 8);
                GL2LDS(bseg + go, Bs + (cb + i * 64) * 8);
            }
            __syncthreads();   // tile staged
            #pragma unroll
            for (int ksub = 0; ksub < 2; ++ksub) {
                const int cgrp = ksub * 4 + (lane >> 4);  // logical 16B chunk in row
                short8 af[2], bf[8];
                #pragma unroll
                for (int qs = 0; qs < 2; ++qs) {
                    const int ar = wv * 32 + qs * 16 + (lane & 15);
                    af[qs] = *reinterpret_cast<const short8*>(As + ar * 64 + ((cgrp ^ (ar & 7)) * 8));
                }
                #pragma unroll
                for (int ns = 0; ns < 8; ++ns) {
                    const int br = ns * 16 + (lane & 15);
                    bf[ns] = *reinterpret_cast<const short8*>(Bs + br * 64 + ((cgrp ^ (br & 7)) * 8));
                }
                #pragma unroll
                for (int qs = 0; qs < 2; ++qs)
                    #pragma unroll
                    for (int ns = 0; ns < 8; ++ns)
                        acc[qs][ns] = __builtin_amdgcn_mfma_f32_16x16x32_bf16(bf[ns], af[qs], acc[qs][ns], 0, 0, 0);
            }
        }

        // in-register selection: per qs, 32 candidates for this thread's fixed query
        #pragma unroll
        for (int qs = 0; qs < 2; ++qs) {
            float m = -1e30f;
            #pragma unroll
            for (int ns = 0; ns < 8; ++ns) {
                float m0 = fmaxf(fmaxf(acc[qs][ns][0], acc[qs][ns][1]),
                                 fmaxf(acc[qs][ns][2], acc[qs][ns][3]));
                m = fmaxf(m, m0);
            }
            if (m > top[qs][TOPK - 1]) {
                #pragma unroll
                for (int ns = 0; ns < 8; ++ns)
                    #pragma unroll
                    for (int r = 0; r < 4; ++r) {
                        float v = acc[qs][ns][r];
                        if (v > top[qs][TOPK - 1]) topk_insert(top[qs], v);
                    }
            }
        }
    }

    // butterfly merge across the 4 lanes sharing each query (lane ^ 16, lane ^ 32)
    #pragma unroll
    for (int qs = 0; qs < 2; ++qs) {
        #pragma unroll
        for (int step = 16; step <= 32; step <<= 1) {
            float other[TOPK];
            #pragma unroll
            for (int i = 0; i < TOPK; ++i) other[i] = __shfl_xor(top[qs][i], step, 64);
            #pragma unroll
            for (int i = 0; i < TOPK; ++i)
                if (other[i] > top[qs][TOPK - 1]) topk_insert(top[qs], other[i]);
        }
    }

    // lanes 0..15 hold the final per-query top-10 for q = qbase + wv*32 + qs*16 + lane
    if ((lane >> 4) == 0) {
        #pragma unroll
        for (int qs = 0; qs < 2; ++qs) {
            const int q = qbase + wv * 32 + qs * 16 + lane;
            float* dst = partial + ((size_t)nc * NQ + q) * TOPK;
            #pragma unroll
            for (int i = 0; i < TOPK; ++i) dst[i] = top[qs][i];
        }
    }
}

// ---------- merge chunks, emit k-th squared distance ----------
__global__ void final_merge(const float* __restrict__ partial, float* __restrict__ out) {
    int q = blockIdx.x * 256 + threadIdx.x;
    if (q >= NQ) return;
    float top[TOPK];
    #pragma unroll
    for (int i = 0; i < TOPK; ++i) top[i] = -1e30f;
    for (int c = 0; c < NCHUNK; ++c) {
        const float* p = partial + ((size_t)c * NQ + q) * TOPK;
        #pragma unroll
        for (int i = 0; i < TOPK; ++i) {
            float x = p[i];
            if (x > top[TOPK - 1]) topk_insert(top, x);
        }
    }
    out[q] = 2.0f - 2.0f * top[TOPK - 1];
}

extern "C" void kernel_launch(void* const* d_in, const int* in_sizes, int n_in,
                              void* d_out, int out_size, void* d_ws, size_t ws_size,
                              hipStream_t stream) {
    const float* features = (const float*)d_in[0];
    const float* dbf      = (const float*)d_in[2];
    float* out = (float*)d_out;

    ushort_t* dbb = (ushort_t*)d_ws;                         // [NPAD][512] bf16   ~102.8 MB
    ushort_t* qbn = dbb + (size_t)NPAD * ND;                 // [2048][512] bf16   ~2 MB
    float* partial = (float*)(qbn + (size_t)NQ * ND);        // [NCHUNK][2048][10] ~4.0 MB

    normalize_rows<<<NPAD / 4, 256, 0, stream>>>(dbf, dbb, NDB, NPAD);
    normalize_rows<<<NQ / 4, 256, 0, stream>>>(features, qbn, NQ, NQ);
    knn_chunk<<<NCHUNK * QTILES, 256, 0, stream>>>(qbn, dbb, partial);
    final_merge<<<(NQ + 255) / 256, 256, 0, stream>>>(partial, out);
}

// Round 5
// 582.653 us; speedup vs baseline: 2.8637x; 1.0098x over previous
//
#include <hip/hip_runtime.h>
#include <hip/hip_bf16.h>

typedef unsigned short ushort_t;
typedef __attribute__((ext_vector_type(8))) short short8;
typedef __attribute__((ext_vector_type(4))) float f32x4;
typedef __attribute__((ext_vector_type(4))) unsigned int uint4v;

#define NQ      2048
#define ND      512
#define NDB     100000
#define TOPK    10
#define NCHUNK  49
#define CHUNK_N 2048                  // 16 tiles * 128
#define NPAD    (NCHUNK * CHUNK_N)    // 100352 >= 100000
#define QTILES  (NQ / 128)            // 16
#define NTILES  (CHUNK_N / 128)       // 16

// async global->LDS, 16B per lane, wave-uniform LDS base + lane*16
#define GL2LDS(gp, lp) __builtin_amdgcn_global_load_lds(                      \
    (const __attribute__((address_space(1))) void*)(gp),                     \
    (__attribute__((address_space(3))) void*)(lp), 16, 0, 0)

// ---------- fp32 -> bf16 (round to nearest even) ----------
static __device__ inline ushort_t f2bf(float x) {
    unsigned u = __float_as_uint(x);
    unsigned r = (u + 0x7FFFu + ((u >> 16) & 1u)) >> 16;
    return (ushort_t)r;
}

// ---------- row L2-normalize, fp32 -> bf16, one wave per row; zero-fill pad rows ----------
__global__ void normalize_rows(const float* __restrict__ in, ushort_t* __restrict__ out,
                               int nvalid, int ntotal) {
    int row  = blockIdx.x * 4 + (threadIdx.x >> 6);
    int lane = threadIdx.x & 63;
    if (row >= ntotal) return;
    uint4v pk;
    if (row >= nvalid) {
        pk[0] = 0u; pk[1] = 0u; pk[2] = 0u; pk[3] = 0u;
    } else {
        const float4* src = reinterpret_cast<const float4*>(in + (size_t)row * ND);
        float4 v0 = src[lane * 2];
        float4 v1 = src[lane * 2 + 1];
        float s = v0.x*v0.x + v0.y*v0.y + v0.z*v0.z + v0.w*v0.w
                + v1.x*v1.x + v1.y*v1.y + v1.z*v1.z + v1.w*v1.w;
        #pragma unroll
        for (int off = 32; off; off >>= 1) s += __shfl_xor(s, off, 64);
        float r = rsqrtf(s);
        pk[0] = (unsigned)f2bf(v0.x * r) | ((unsigned)f2bf(v0.y * r) << 16);
        pk[1] = (unsigned)f2bf(v0.z * r) | ((unsigned)f2bf(v0.w * r) << 16);
        pk[2] = (unsigned)f2bf(v1.x * r) | ((unsigned)f2bf(v1.y * r) << 16);
        pk[3] = (unsigned)f2bf(v1.z * r) | ((unsigned)f2bf(v1.w * r) << 16);
    }
    *reinterpret_cast<uint4v*>(out + (size_t)row * ND + lane * 8) = pk;
}

__device__ inline void topk_insert(float (&top)[TOPK], float x) {
    #pragma unroll
    for (int i = 0; i < TOPK; ++i) {
        float mx = fmaxf(top[i], x);
        x = fminf(top[i], x);
        top[i] = mx;
    }
}

// ---------- fused GEMM + per-chunk top-10 ----------
// 256 threads, 4 waves; wave wv owns queries [wv*32, wv*32+32) x 128 n per tile.
// A K-panel (this wave's 32 q-rows, all K=512) lives in registers, loaded once.
// B double-buffered in LDS, 1 barrier per K-step, next-step stage issued before compute.
// SWAPPED mfma(B,A): acc[qs][ns][r] = score[n = ns*16+(lane>>4)*4+r][q = qs*16+(lane&15)]
__global__ __launch_bounds__(256, 2)
void knn_chunk(const ushort_t* __restrict__ qb, const ushort_t* __restrict__ dbb,
               float* __restrict__ partial) {
    const int bid = blockIdx.x;
    const int qt = bid & (QTILES - 1);
    const int nc = bid >> 4;           // QTILES == 16
    const int t = threadIdx.x, lane = t & 63, wv = t >> 6;

    __shared__ __align__(16) ushort_t Bs[2][128 * 64];

    // ---- A K-panel in registers: af[qs][kk], kk = K/32 slice (16 total) ----
    // B-operand layout of mfma_16x16x32: col(q) = lane&15, k = (lane>>4)*8 + j
    short8 af[2][16];
    {
        const ushort_t* aseg = qb + (size_t)(qt * 128) * ND;
        #pragma unroll
        for (int qs = 0; qs < 2; ++qs) {
            const ushort_t* ap = aseg + (size_t)(wv * 32 + qs * 16 + (lane & 15)) * ND + (lane >> 4) * 8;
            #pragma unroll
            for (int kk = 0; kk < 16; ++kk)
                af[qs][kk] = *reinterpret_cast<const short8*>(ap + kk * 32);
        }
    }

    float top[2][TOPK];
    #pragma unroll
    for (int qs = 0; qs < 2; ++qs)
        #pragma unroll
        for (int i = 0; i < TOPK; ++i) top[qs][i] = -1e30f;

    const size_t nchunkbase = (size_t)nc * CHUNK_N;
    const int cb = wv * 256;          // wave's 16B-chunk base among the tile's 1024 chunks

    // stage one 128x64 B K-slice (16KB) into buffer b; both-sides XOR swizzle:
    // inverse-swizzled global source + linear LDS dest (gload_lds requirement)
    auto stageB = [&](size_t rowbase, int kbase, int b) {
        const ushort_t* bseg = dbb + rowbase * ND;
        #pragma unroll
        for (int i = 0; i < 4; ++i) {
            const int cid = cb + i * 64 + lane;
            const int row = cid >> 3;
            const int c   = (cid & 7) ^ (row & 7);
            GL2LDS(bseg + (size_t)row * ND + kbase + c * 8, &Bs[b][(cb + i * 64) * 8]);
        }
    };

    stageB(nchunkbase, 0, 0);   // prologue: (nt=0, ks=0) -> buf0

    #pragma unroll 1
    for (int nt = 0; nt < NTILES; ++nt) {
        f32x4 acc[2][8];
        #pragma unroll
        for (int a = 0; a < 2; ++a)
            #pragma unroll
            for (int b = 0; b < 8; ++b)
                acc[a][b] = (f32x4){0.f, 0.f, 0.f, 0.f};

        #pragma unroll
        for (int ks = 0; ks < 8; ++ks) {
            __syncthreads();                       // buf[ks&1] staged; prev reads done
            const int cur = ks & 1;
            if (ks < 7)                 stageB(nchunkbase + nt * 128, (ks + 1) * 64, cur ^ 1);
            else if (nt + 1 < NTILES)   stageB(nchunkbase + (nt + 1) * 128, 0, cur ^ 1);
            #pragma unroll
            for (int ksub = 0; ksub < 2; ++ksub) {
                const int j0 = (ksub * 4 + (lane >> 4)) ^ (lane & 7);   // swizzled 16B-chunk in row
                short8 bf[8];
                #pragma unroll
                for (int ns = 0; ns < 8; ++ns)
                    bf[ns] = *reinterpret_cast<const short8*>(&Bs[cur][(ns * 16 + (lane & 15)) * 64 + j0 * 8]);
                #pragma unroll
                for (int qs = 0; qs < 2; ++qs)
                    #pragma unroll
                    for (int ns = 0; ns < 8; ++ns)
                        acc[qs][ns] = __builtin_amdgcn_mfma_f32_16x16x32_bf16(bf[ns], af[qs][ks * 2 + ksub], acc[qs][ns], 0, 0, 0);
            }
        }

        // in-register selection; next n-tile's first B-stage is in flight underneath
        #pragma unroll
        for (int qs = 0; qs < 2; ++qs) {
            float m = -1e30f;
            #pragma unroll
            for (int ns = 0; ns < 8; ++ns) {
                float m0 = fmaxf(fmaxf(acc[qs][ns][0], acc[qs][ns][1]),
                                 fmaxf(acc[qs][ns][2], acc[qs][ns][3]));
                m = fmaxf(m, m0);
            }
            if (m > top[qs][TOPK - 1]) {
                #pragma unroll
                for (int ns = 0; ns < 8; ++ns)
                    #pragma unroll
                    for (int r = 0; r < 4; ++r) {
                        float v = acc[qs][ns][r];
                        if (v > top[qs][TOPK - 1]) topk_insert(top[qs], v);
                    }
            }
        }
    }

    // butterfly merge across the 4 lanes sharing each query (lane ^ 16, lane ^ 32)
    #pragma unroll
    for (int qs = 0; qs < 2; ++qs) {
        #pragma unroll
        for (int step = 16; step <= 32; step <<= 1) {
            float other[TOPK];
            #pragma unroll
            for (int i = 0; i < TOPK; ++i) other[i] = __shfl_xor(top[qs][i], step, 64);
            #pragma unroll
            for (int i = 0; i < TOPK; ++i)
                if (other[i] > top[qs][TOPK - 1]) topk_insert(top[qs], other[i]);
        }
    }

    // lanes 0..15 hold the final per-query top-10 for q = qt*128 + wv*32 + qs*16 + lane
    if ((lane >> 4) == 0) {
        #pragma unroll
        for (int qs = 0; qs < 2; ++qs) {
            const int q = qt * 128 + wv * 32 + qs * 16 + lane;
            float* dst = partial + ((size_t)nc * NQ + q) * TOPK;
            #pragma unroll
            for (int i = 0; i < TOPK; ++i) dst[i] = top[qs][i];
        }
    }
}

// ---------- merge chunks, emit k-th squared distance ----------
__global__ void final_merge(const float* __restrict__ partial, float* __restrict__ out) {
    int q = blockIdx.x * 256 + threadIdx.x;
    if (q >= NQ) return;
    float top[TOPK];
    #pragma unroll
    for (int i = 0; i < TOPK; ++i) top[i] = -1e30f;
    for (int c = 0; c < NCHUNK; ++c) {
        const float* p = partial + ((size_t)c * NQ + q) * TOPK;
        #pragma unroll
        for (int i = 0; i < TOPK; ++i) {
            float x = p[i];
            if (x > top[TOPK - 1]) topk_insert(top, x);
        }
    }
    out[q] = 2.0f - 2.0f * top[TOPK - 1];
}

extern "C" void kernel_launch(void* const* d_in, const int* in_sizes, int n_in,
                              void* d_out, int out_size, void* d_ws, size_t ws_size,
                              hipStream_t stream) {
    const float* features = (const float*)d_in[0];
    const float* dbf      = (const float*)d_in[2];
    float* out = (float*)d_out;

    ushort_t* dbb = (ushort_t*)d_ws;                         // [NPAD][512] bf16   ~102.8 MB
    ushort_t* qbn = dbb + (size_t)NPAD * ND;                 // [2048][512] bf16   ~2 MB
    float* partial = (float*)(qbn + (size_t)NQ * ND);        // [NCHUNK][2048][10] ~4.0 MB

    normalize_rows<<<NPAD / 4, 256, 0, stream>>>(dbf, dbb, NDB, NPAD);
    normalize_rows<<<NQ / 4, 256, 0, stream>>>(features, qbn, NQ, NQ);
    knn_chunk<<<NCHUNK * QTILES, 256, 0, stream>>>(qbn, dbb, partial);
    final_merge<<<(NQ + 255) / 256, 256, 0, stream>>>(partial, out);
}